// Round 6
// baseline (256.855 us; speedup 1.0000x reference)
//
#include <hip/hip_runtime.h>
#include <cfloat>
#include <cmath>

#define DEVINL __device__ __forceinline__

constexpr int N_ = 4, C_ = 21, H_ = 512, W_ = 512;
constexpr int P_ = 171;           // pooled H/W
constexpr int Q_ = 169;           // point grid: P-3+1
constexpr int NC_ = N_ * C_;      // 84
constexpr int HW_ = H_ * W_;      // 262144 = 2^18
constexpr int PROW_ = 192;        // padded row stride: 768 B = 6 full 128B lines
                                  // (was 172 = 688 B -> every row write/read
                                  //  straddled partial lines; WRITE_SIZE 34 MB
                                  //  vs 20 MB ideal)
constexpr int PPAD_ = PROW_ * P_; // 32832 per (n,c) image
constexpr int NCOV_ = 189;        // 9 + 9 + 45 + 45 + 81
constexpr float EPS_ = 5e-4f;
constexpr int RC_ = 43;           // rows per k_cov chunk (4 chunks cover 169)
constexpr int G_ = 43;            // col-quads per row

constexpr int NB_CE = N_ * HW_ / 4 / 256;            // 1024 CE blocks
constexpr int NB_PL = (NC_ * P_ * G_ + 255) / 256;   // 2413 pool blocks

typedef float f4_t __attribute__((ext_vector_type(4)));

DEVINL constexpr int tstart(int d) { return d * 9 - d * (d - 1) / 2; }

// ---------------------------------------------------------------------------
// DPP wave reduction: pure VALU, no DS-pipe traffic. Total lands in lane 63.
// ---------------------------------------------------------------------------
template <int CTRL>
DEVINL float dpp_add(float v) {
    int x = __builtin_amdgcn_update_dpp(0, __float_as_int(v), CTRL, 0xF, 0xF, false);
    return v + __int_as_float(x);
}

DEVINL float wave_sum63(float v) {
    v = dpp_add<0x111>(v);   // row_shr:1
    v = dpp_add<0x112>(v);   // row_shr:2
    v = dpp_add<0x114>(v);   // row_shr:4
    v = dpp_add<0x118>(v);   // row_shr:8
    v = dpp_add<0x142>(v);   // row_bcast:15
    v = dpp_add<0x143>(v);   // row_bcast:31
    return v;                // total in lane 63
}

// ---------------------------------------------------------------------------
// bits_cell: packed one-hot + 3x3 validity bits for pooled cell (i,j).
// Verbatim per-cell logic of the old k_bits kernel (now inlined in the pool
// role: saves a kernel launch + the pack round-trip; target is L2-hot).
// ---------------------------------------------------------------------------
DEVINL unsigned bits_cell(const int* __restrict__ tb, int i, int j) {
    int hl = 3 * i - 1; if (hl < 0) hl = 0;
    int wl = 3 * j - 1; if (wl < 0) wl = 0;
    int hmax = 3 * i + 1, wmax = 3 * j + 1;
    unsigned oh = 0, px = 0;
#pragma unroll
    for (int r = 0; r < 3; ++r) {
        int hh = hl + r;
        bool hv = hh <= hmax;
        const int* trow = tb + hh * W_;
#pragma unroll
        for (int dc = 0; dc < 3; ++dc) {
            int ww = wl + dc;
            int t = trow[ww];
            if (hv && (ww <= wmax) && t >= 0 && t < C_) {
                oh |= 1u << t;
                px |= 1u << (r * 3 + dc);
            }
        }
    }
    return oh | (px << 23);
}

// ---------------------------------------------------------------------------
// do_cell: masked 3x3 max + sigmoid + clip for one pooled cell.
// ---------------------------------------------------------------------------
template <int IDX>
DEVINL void do_cell(const float (&f)[3][16], unsigned pk, int c, float* prp, float* lap) {
    unsigned px = pk >> 23;
    float vm = -FLT_MAX;
#pragma unroll
    for (int r = 0; r < 3; ++r)
#pragma unroll
        for (int dc = 0; dc < 3; ++dc)
            vm = fmaxf(vm, ((px >> (r * 3 + dc)) & 1u) ? f[r][IDX + dc] : -FLT_MAX);
    float p = __builtin_amdgcn_rcpf(1.f + __expf(-vm));
    p = fminf(fmaxf(p, 1e-6f), 1.f);
    *prp = p;
    *lap = ((pk >> c) & 1u) ? 1.f : 0.f;
}

// ---------------------------------------------------------------------------
// k_mix: CE + pool role-split blocks. R5 post-mortem: every structural
// variant of the score stage pins at ~2 TB/s. Theory: score planes are
// exactly 2^20 B apart; all waves walk the 21 planes in LOCKSTEP (same code,
// same class order) -> a wave's loads share low 20 address bits -> same DRAM
// channels/rows + same L2 slice across the whole chip -> row-buffer thrash.
// Fix: per-wave rotation of the 3 class-batch execution order
// (phase = (bid+wv)%3). Arithmetic is kept IDENTICAL: each batch's partial
// sum is computed in canonical ascending order and the three partials are
// combined in fixed order (se0+se1)+se2, so execution order doesn't touch
// the FP result.
// ---------------------------------------------------------------------------
__global__ __launch_bounds__(256) void k_mix(const float* __restrict__ score,
                                             const int* __restrict__ target,
                                             float* __restrict__ pr,
                                             float* __restrict__ la,
                                             float* __restrict__ cov) {
    int bid = blockIdx.x;
    int t = threadIdx.x;
    int wv = t >> 6, lane = t & 63;

    if (bid < NB_CE) {
        // ---- CE role: thread per 4 pixels, batch-rotated plane walk -------
        __shared__ float rn[4], rc[4];
        int tid = bid * 256 + t;
        int p0 = tid * 4;
        int n = p0 >> 18;
        int hw = p0 & (HW_ - 1);
        const float* sp = score + (size_t)n * C_ * HW_ + hw;
        int4 t4 = *(const int4*)(target + p0);

        float4 se0 = {0.f, 0.f, 0.f, 0.f}, se1 = se0, se2 = se0;
        float4 stgt = {0.f, 0.f, 0.f, 0.f};
        int phase = (bid + wv) % 3;
        f4_t s[7];
#pragma unroll
        for (int kk = 0; kk < 3; ++kk) {
            int b = kk + phase; if (b >= 3) b -= 3;   // batch index 0..2
            int cb = b * 7;
#pragma unroll
            for (int u = 0; u < 7; ++u)
                s[u] = *(const f4_t*)(sp + (size_t)(cb + u) * HW_);
            asm volatile("" : "+v"(s[0]), "+v"(s[1]), "+v"(s[2]), "+v"(s[3]),
                              "+v"(s[4]), "+v"(s[5]), "+v"(s[6]));
            float4 acc = {0.f, 0.f, 0.f, 0.f};
#pragma unroll
            for (int u = 0; u < 7; ++u) {
                int c = cb + u;
                acc.x += __expf(s[u].x);
                acc.y += __expf(s[u].y);
                acc.z += __expf(s[u].z);
                acc.w += __expf(s[u].w);
                if (t4.x == c) stgt.x = s[u].x;
                if (t4.y == c) stgt.y = s[u].y;
                if (t4.z == c) stgt.z = s[u].z;
                if (t4.w == c) stgt.w = s[u].w;
            }
            if (b == 0) se0 = acc;
            else if (b == 1) se1 = acc;
            else se2 = acc;
        }
        // canonical combine order -> bitwise-identical to unrotated kernel
        float4 se;
        se.x = (se0.x + se1.x) + se2.x;
        se.y = (se0.y + se1.y) + se2.y;
        se.z = (se0.z + se1.z) + se2.z;
        se.w = (se0.w + se1.w) + se2.w;

        float nll = 0.f, cnt = 0.f;
        if (t4.x != 255) { nll += __logf(se.x) - stgt.x; cnt += 1.f; }
        if (t4.y != 255) { nll += __logf(se.y) - stgt.y; cnt += 1.f; }
        if (t4.z != 255) { nll += __logf(se.z) - stgt.z; cnt += 1.f; }
        if (t4.w != 255) { nll += __logf(se.w) - stgt.w; cnt += 1.f; }

        nll = wave_sum63(nll);
        cnt = wave_sum63(cnt);
        if (lane == 63) { rn[wv] = nll; rc[wv] = cnt; }
        __syncthreads();
        if (t == 0)
            atomicAdd(&cov[NC_ * NCOV_ + 0], rn[0] + rn[1] + rn[2] + rn[3]);
        if (t == 64)
            atomicAdd(&cov[NC_ * NCOV_ + 1], rc[0] + rc[1] + rc[2] + rc[3]);
    } else {
        // ---- Pool role: thread per (n,c,i,g); pack bits computed inline ---
        int tid = (bid - NB_CE) * 256 + t;
        if (tid >= NC_ * P_ * G_) return;
        int g = tid % G_;
        int rest = tid / G_;
        int i = rest % P_;
        int ncidx = rest / P_;
        int n = ncidx / C_;
        int c = ncidx - n * C_;

        const int* tb = target + (size_t)n * HW_;
        unsigned pk0 = bits_cell(tb, i, 4 * g + 0);
        unsigned pk1 = bits_cell(tb, i, 4 * g + 1);
        unsigned pk2 = bits_cell(tb, i, 4 * g + 2);
        unsigned pk3 = (4 * g + 3 < P_) ? bits_cell(tb, i, 4 * g + 3) : 0u;

        int hl = 3 * i - 1; if (hl < 0) hl = 0;
        int b = (g == 0) ? 0 : 12 * g - 4;
        int o3 = (b + 15 < W_) ? 12 : 8;

        const float* sb = score + (size_t)ncidx * HW_ + (size_t)hl * W_ + b;
        float f[3][16];
#pragma unroll
        for (int r = 0; r < 3; ++r) {
            const float* rp = sb + r * W_;
            float4 q0 = *(const float4*)(rp);
            float4 q1 = *(const float4*)(rp + 4);
            float4 q2 = *(const float4*)(rp + 8);
            float4 q3 = *(const float4*)(rp + o3);
            f[r][0] = q0.x;  f[r][1] = q0.y;  f[r][2] = q0.z;  f[r][3] = q0.w;
            f[r][4] = q1.x;  f[r][5] = q1.y;  f[r][6] = q1.z;  f[r][7] = q1.w;
            f[r][8] = q2.x;  f[r][9] = q2.y;  f[r][10] = q2.z; f[r][11] = q2.w;
            f[r][12] = q3.x; f[r][13] = q3.y; f[r][14] = q3.z; f[r][15] = q3.w;
        }

        size_t ob = (size_t)ncidx * PPAD_ + (size_t)i * PROW_ + 4 * g;
        if (g == 0) {
            do_cell<0>(f, pk0, c, pr + ob + 0, la + ob + 0);
            do_cell<2>(f, pk1, c, pr + ob + 1, la + ob + 1);
            do_cell<5>(f, pk2, c, pr + ob + 2, la + ob + 2);
            do_cell<8>(f, pk3, c, pr + ob + 3, la + ob + 3);
        } else {
            do_cell<3>(f, pk0, c, pr + ob + 0, la + ob + 0);
            do_cell<6>(f, pk1, c, pr + ob + 1, la + ob + 1);
            do_cell<9>(f, pk2, c, pr + ob + 2, la + ob + 2);
            if (4 * g + 3 < P_)
                do_cell<12>(f, pk3, c, pr + ob + 3, la + ob + 3);
        }
    }
}

// ---------------------------------------------------------------------------
// k_cov v6 (kept from R5 -- dropped out of top-5): global reads (L2-hot),
// grid (84, 4 chunks, 8 parts) = 2688 blocks, every part <=27 register-
// resident accumulators, DPP reductions, LDS 432 B.
//   z=0: SAA d<3 (24)   z=1: SAA d>=3 (21)   z=2: SBB d<3 (24)
//   z=3: SBB d>=3 (21)  z=4..6: SAB a-row RA=z-4 (27)  z=7: s1A+s1B (18)
// ---------------------------------------------------------------------------
template <int D0, int D1>
DEVINL void cov_tri(const float* __restrict__ X, float* __restrict__ cov,
                    int nc, int r0, int rend, int s2base,
                    int tid, float (*red)[27]) {
    constexpr int NS2 = ((9 - D0) * (10 - D0) - (9 - D1) * (10 - D1)) / 2;
    constexpr int RLO = D0 / 3;
    constexpr int KOFF = tstart(D0);
    float s2[NS2];
#pragma unroll
    for (int k = 0; k < NS2; ++k) s2[k] = 0.f;

    int nitems = (rend - r0) * G_;
    for (int idx = tid; idx < nitems; idx += 256) {
        int lr = idx / G_;
        int q = idx - lr * G_;
        int x0 = q * 4;
        const float* base = X + (size_t)(r0 + lr) * PROW_ + x0;
        float v[3][8];
#pragma unroll
        for (int r = RLO; r < 3; ++r) {
            float4 u0 = *(const float4*)(base + r * PROW_);
            float4 u1 = *(const float4*)(base + r * PROW_ + 4);
            v[r][0] = u0.x; v[r][1] = u0.y; v[r][2] = u0.z; v[r][3] = u0.w;
            v[r][4] = u1.x; v[r][5] = u1.y; v[r][6] = u1.z; v[r][7] = u1.w;
        }
#pragma unroll
        for (int p = 0; p < 4; ++p) {
            if (x0 + p < Q_) {
                int k = 0;
#pragma unroll
                for (int d = D0; d < D1; ++d)
#pragma unroll
                    for (int e = d; e < 9; ++e) {
                        s2[k] += v[d / 3][p + d % 3] * v[e / 3][p + e % 3];
                        ++k;
                    }
            }
        }
    }

    int lane = tid & 63, wv = tid >> 6;
#pragma unroll
    for (int k = 0; k < NS2; ++k) {
        float v2 = wave_sum63(s2[k]);
        if (lane == 63) red[wv][k] = v2;
    }
    __syncthreads();
    if (tid < NS2) {
        float v2 = red[0][tid] + red[1][tid] + red[2][tid] + red[3][tid];
        atomicAdd(&cov[nc * NCOV_ + s2base + KOFF + tid], v2);
    }
}

template <int RA>
DEVINL void cov_ab(const float* __restrict__ A, const float* __restrict__ B,
                   float* __restrict__ cov, int nc, int r0, int rend,
                   int tid, float (*red)[27]) {
    float sab[27];
#pragma unroll
    for (int k = 0; k < 27; ++k) sab[k] = 0.f;

    int nitems = (rend - r0) * G_;
    for (int idx = tid; idx < nitems; idx += 256) {
        int lr = idx / G_;
        int q = idx - lr * G_;
        int x0 = q * 4;
        size_t off = (size_t)(r0 + lr) * PROW_ + x0;
        float a[8];
        {
            float4 u0 = *(const float4*)(A + off + RA * PROW_);
            float4 u1 = *(const float4*)(A + off + RA * PROW_ + 4);
            a[0] = u0.x; a[1] = u0.y; a[2] = u0.z; a[3] = u0.w;
            a[4] = u1.x; a[5] = u1.y; a[6] = u1.z; a[7] = u1.w;
        }
#pragma unroll
        for (int r = 0; r < 3; ++r) {
            float b[8];
            {
                float4 w0 = *(const float4*)(B + off + r * PROW_);
                float4 w1 = *(const float4*)(B + off + r * PROW_ + 4);
                b[0] = w0.x; b[1] = w0.y; b[2] = w0.z; b[3] = w0.w;
                b[4] = w1.x; b[5] = w1.y; b[6] = w1.z; b[7] = w1.w;
            }
#pragma unroll
            for (int p = 0; p < 4; ++p) {
                if (x0 + p < Q_) {
#pragma unroll
                    for (int dm = 0; dm < 3; ++dm)
#pragma unroll
                        for (int e2 = 0; e2 < 3; ++e2)
                            sab[dm * 9 + r * 3 + e2] += a[p + dm] * b[p + e2];
                }
            }
        }
    }

    int lane = tid & 63, wv = tid >> 6;
#pragma unroll
    for (int k = 0; k < 27; ++k) {
        float v2 = wave_sum63(sab[k]);
        if (lane == 63) red[wv][k] = v2;
    }
    __syncthreads();
    if (tid < 27) {
        float v2 = red[0][tid] + red[1][tid] + red[2][tid] + red[3][tid];
        atomicAdd(&cov[nc * NCOV_ + 108 + RA * 27 + tid], v2);
    }
}

DEVINL void cov_s1(const float* __restrict__ LA, const float* __restrict__ PR,
                   float* __restrict__ cov, int nc, int r0, int rend,
                   int tid, float (*red)[27]) {
    float s1a[9], s1b[9];
#pragma unroll
    for (int k = 0; k < 9; ++k) { s1a[k] = 0.f; s1b[k] = 0.f; }

    int nitems = (rend - r0) * G_;
    for (int idx = tid; idx < nitems; idx += 256) {
        int lr = idx / G_;
        int q = idx - lr * G_;
        int x0 = q * 4;
        size_t off = (size_t)(r0 + lr) * PROW_ + x0;
#pragma unroll
        for (int r = 0; r < 3; ++r) {
            float va[8], vb[8];
            {
                float4 u0 = *(const float4*)(LA + off + r * PROW_);
                float4 u1 = *(const float4*)(LA + off + r * PROW_ + 4);
                va[0] = u0.x; va[1] = u0.y; va[2] = u0.z; va[3] = u0.w;
                va[4] = u1.x; va[5] = u1.y; va[6] = u1.z; va[7] = u1.w;
                float4 w0 = *(const float4*)(PR + off + r * PROW_);
                float4 w1 = *(const float4*)(PR + off + r * PROW_ + 4);
                vb[0] = w0.x; vb[1] = w0.y; vb[2] = w0.z; vb[3] = w0.w;
                vb[4] = w1.x; vb[5] = w1.y; vb[6] = w1.z; vb[7] = w1.w;
            }
#pragma unroll
            for (int p = 0; p < 4; ++p) {
                if (x0 + p < Q_) {
#pragma unroll
                    for (int dc = 0; dc < 3; ++dc) {
                        s1a[r * 3 + dc] += va[p + dc];
                        s1b[r * 3 + dc] += vb[p + dc];
                    }
                }
            }
        }
    }

    int lane = tid & 63, wv = tid >> 6;
#pragma unroll
    for (int k = 0; k < 9; ++k) {
        float v2 = wave_sum63(s1a[k]);
        if (lane == 63) red[wv][k] = v2;
    }
#pragma unroll
    for (int k = 0; k < 9; ++k) {
        float v2 = wave_sum63(s1b[k]);
        if (lane == 63) red[wv][9 + k] = v2;
    }
    __syncthreads();
    if (tid < 18) {
        float v2 = red[0][tid] + red[1][tid] + red[2][tid] + red[3][tid];
        atomicAdd(&cov[nc * NCOV_ + tid], v2);   // 0..8 = s1A, 9..17 = s1B
    }
}

__global__ __launch_bounds__(256) void k_cov(const float* __restrict__ la,
                                             const float* __restrict__ pr,
                                             float* __restrict__ cov) {
    __shared__ float red[4][27];
    int nc = blockIdx.x;
    int chunk = blockIdx.y;
    int part = blockIdx.z;
    int r0 = chunk * RC_;
    int rend = r0 + RC_;
    if (rend > Q_) rend = Q_;
    int tid = threadIdx.x;
    const float* LA = la + (size_t)nc * PPAD_;
    const float* PR = pr + (size_t)nc * PPAD_;

    switch (part) {
        case 0: cov_tri<0, 3>(LA, cov, nc, r0, rend, 18, tid, red); break;
        case 1: cov_tri<3, 9>(LA, cov, nc, r0, rend, 18, tid, red); break;
        case 2: cov_tri<0, 3>(PR, cov, nc, r0, rend, 63, tid, red); break;
        case 3: cov_tri<3, 9>(PR, cov, nc, r0, rend, 63, tid, red); break;
        case 4: cov_ab<0>(LA, PR, cov, nc, r0, rend, tid, red); break;
        case 5: cov_ab<1>(LA, PR, cov, nc, r0, rend, tid, red); break;
        case 6: cov_ab<2>(LA, PR, cov, nc, r0, rend, tid, red); break;
        case 7: cov_s1(LA, PR, cov, nc, r0, rend, tid, red); break;
    }
}

// ---------------------------------------------------------------------------
// k_final: per-(n,c) 9x9 algebra. UNCHANGED.
// ---------------------------------------------------------------------------
__global__ __launch_bounds__(128) void k_final(const float* __restrict__ cov,
                                               float* __restrict__ out) {
    __shared__ float red[128];
    int t = threadIdx.x;
    float my = 0.f;
    if (t < NC_) {
        const float* S = cov + t * NCOV_;
        const float Lf = (float)(Q_ * Q_);  // 28561
        float sA[9], sB[9];
#pragma unroll
        for (int d = 0; d < 9; ++d) { sA[d] = S[d]; sB[d] = S[9 + d]; }
        float laC[45], M[45], Cm[81];
        {
            int k = 0;
#pragma unroll
            for (int d = 0; d < 9; ++d)
#pragma unroll
                for (int e = d; e < 9; ++e) {
                    laC[k] = S[18 + k] - sA[d] * sA[e] / Lf;
                    M[k] = S[63 + k] - sB[d] * sB[e] / Lf + (d == e ? EPS_ : 0.f);
                    ++k;
                }
#pragma unroll
            for (int d = 0; d < 9; ++d)
#pragma unroll
                for (int e = 0; e < 9; ++e)
                    Cm[d * 9 + e] = S[108 + d * 9 + e] - sA[d] * sB[e] / Lf;
        }
#pragma unroll
        for (int j = 0; j < 9; ++j) {
            float s = M[tstart(j)];
#pragma unroll
            for (int k = 0; k < j; ++k) { float l = M[tstart(k) + (j - k)]; s -= l * l; }
            float dj = sqrtf(fmaxf(s, 1e-30f));
            M[tstart(j)] = dj;
            float inv = 1.f / dj;
#pragma unroll
            for (int i = j + 1; i < 9; ++i) {
                float s2 = M[tstart(j) + (i - j)];
#pragma unroll
                for (int k = 0; k < j; ++k)
                    s2 -= M[tstart(k) + (i - k)] * M[tstart(k) + (j - k)];
                M[tstart(j) + (i - j)] = s2 * inv;
            }
        }
#pragma unroll
        for (int p = 0; p < 9; ++p) {
#pragma unroll
            for (int i = 0; i < 9; ++i) {
                float s = Cm[p * 9 + i];
#pragma unroll
                for (int k = 0; k < i; ++k)
                    s -= M[tstart(k) + (i - k)] * Cm[p * 9 + k];
                Cm[p * 9 + i] = s / M[tstart(i)];
            }
        }
#pragma unroll
        for (int d = 0; d < 9; ++d)
#pragma unroll
            for (int e = d; e < 9; ++e) {
                float s = 0.f;
#pragma unroll
                for (int i = 0; i < 9; ++i) s += Cm[d * 9 + i] * Cm[e * 9 + i];
                laC[tstart(d) + (e - d)] -= s;
                if (d == e) laC[tstart(d)] += EPS_;
            }
        float rmi = 0.f;
#pragma unroll
        for (int j = 0; j < 9; ++j) {
            float s = laC[tstart(j)];
#pragma unroll
            for (int k = 0; k < j; ++k) { float l = laC[tstart(k) + (j - k)]; s -= l * l; }
            float dj = sqrtf(fmaxf(s, 0.f));
            laC[tstart(j)] = dj;
            float inv = 1.f / fmaxf(dj, 1e-30f);
#pragma unroll
            for (int i = j + 1; i < 9; ++i) {
                float s2 = laC[tstart(j) + (i - j)];
#pragma unroll
                for (int k = 0; k < j; ++k)
                    s2 -= laC[tstart(k) + (i - k)] * laC[tstart(k) + (j - k)];
                laC[tstart(j) + (i - j)] = s2 * inv;
            }
            rmi += __logf(dj + 1e-8f);
        }
        my = rmi;
    }
    red[t] = my;
    __syncthreads();
#pragma unroll
    for (int o = 64; o > 0; o >>= 1) {
        if (t < o) red[t] += red[t + o];
        __syncthreads();
    }
    if (t == 0) {
        float rmi_total = red[0] / 36.f;  // / (N * HALF_D)
        float ce = cov[NC_ * NCOV_ + 0] / cov[NC_ * NCOV_ + 1];
        out[0] = 0.5f * ce + 0.5f * rmi_total;
    }
}

extern "C" void kernel_launch(void* const* d_in, const int* in_sizes, int n_in,
                              void* d_out, int out_size, void* d_ws, size_t ws_size,
                              hipStream_t stream) {
    const float* score = (const float*)d_in[0];
    const int* target = (const int*)d_in[1];
    float* pr = (float*)d_ws;
    float* la = pr + (size_t)NC_ * PPAD_;
    float* cov = la + (size_t)NC_ * PPAD_;              // NC_*NCOV_ + 2 floats
    hipMemsetAsync(cov, 0, (size_t)(NC_ * NCOV_ + 2) * sizeof(float), stream);

    k_mix<<<dim3(NB_CE + NB_PL), dim3(256), 0, stream>>>(score, target, pr, la, cov);
    k_cov<<<dim3(NC_, 4, 8), dim3(256), 0, stream>>>(la, pr, cov);
    k_final<<<dim3(1), dim3(128), 0, stream>>>(cov, (float*)d_out);
}

// Round 7
// 251.071 us; speedup vs baseline: 1.0230x; 1.0230x over previous
//
#include <hip/hip_runtime.h>
#include <cfloat>
#include <cmath>

#define DEVINL __device__ __forceinline__

constexpr int N_ = 4, C_ = 21, H_ = 512, W_ = 512;
constexpr int P_ = 171;           // pooled H/W
constexpr int Q_ = 169;           // point grid: P-3+1
constexpr int NC_ = N_ * C_;      // 84
constexpr int HW_ = H_ * W_;      // 262144 = 2^18
constexpr int PP_ = 29241;        // P_*P_ (pack layout, unpadded)
constexpr int PROW_ = 192;        // padded row stride: 768 B = 6 full 128B lines
constexpr int PPAD_ = PROW_ * P_; // 32832 per (n,c) image
constexpr int NCOV_ = 189;        // 9 + 9 + 45 + 45 + 81
constexpr float EPS_ = 5e-4f;
constexpr int RC_ = 43;           // rows per k_cov chunk (4 chunks cover 169)
constexpr int G_ = 43;            // col-quads per row

constexpr int NB_CE = N_ * HW_ / 4 / 256;            // 1024 CE blocks
constexpr int NB_PL = (NC_ * P_ * G_ + 255) / 256;   // 2413 pool blocks

typedef float f4_t __attribute__((ext_vector_type(4)));
typedef __attribute__((address_space(1))) const void gas_void;
typedef __attribute__((address_space(3))) void las_void;

DEVINL constexpr int tstart(int d) { return d * 9 - d * (d - 1) / 2; }

// ---------------------------------------------------------------------------
// DPP wave reduction: pure VALU, no DS-pipe traffic. Total lands in lane 63.
// ---------------------------------------------------------------------------
template <int CTRL>
DEVINL float dpp_add(float v) {
    int x = __builtin_amdgcn_update_dpp(0, __float_as_int(v), CTRL, 0xF, 0xF, false);
    return v + __int_as_float(x);
}

DEVINL float wave_sum63(float v) {
    v = dpp_add<0x111>(v);   // row_shr:1
    v = dpp_add<0x112>(v);   // row_shr:2
    v = dpp_add<0x114>(v);   // row_shr:4
    v = dpp_add<0x118>(v);   // row_shr:8
    v = dpp_add<0x142>(v);   // row_bcast:15
    v = dpp_add<0x143>(v);   // row_bcast:31
    return v;                // total in lane 63
}

// ---------------------------------------------------------------------------
// k_bits: thread per pooled cell (n,i,j) -> packed one-hot + validity bits.
// Block 0 additionally zeroes cov (runs before k_mix/k_cov on the stream ->
// replaces the hipMemsetAsync dispatch).
// ---------------------------------------------------------------------------
__global__ __launch_bounds__(256) void k_bits(const int* __restrict__ target,
                                              unsigned* __restrict__ pack,
                                              float* __restrict__ cov) {
    int t = threadIdx.x;
    if (blockIdx.x == 0) {
        for (int k = t; k < NC_ * NCOV_ + 2; k += 256) cov[k] = 0.f;
    }
    int tid = blockIdx.x * 256 + t;
    if (tid >= N_ * PP_) return;
    int cell = tid % PP_;
    int n = tid / PP_;
    int j = cell % P_;
    int i = cell / P_;
    int hl = 3 * i - 1; if (hl < 0) hl = 0;
    int wl = 3 * j - 1; if (wl < 0) wl = 0;
    int hmax = 3 * i + 1, wmax = 3 * j + 1;
    const int* tb = target + (size_t)n * HW_;
    unsigned oh = 0, px = 0;
#pragma unroll
    for (int r = 0; r < 3; ++r) {
        int hh = hl + r;
        bool hv = hh <= hmax;
        const int* trow = tb + hh * W_;
#pragma unroll
        for (int dc = 0; dc < 3; ++dc) {
            int ww = wl + dc;
            int tv = trow[ww];
            if (hv && (ww <= wmax) && tv >= 0 && tv < C_) {
                oh |= 1u << tv;
                px |= 1u << (r * 3 + dc);
            }
        }
    }
    pack[tid] = oh | (px << 23);
}

// ---------------------------------------------------------------------------
// do_cell: masked 3x3 max + sigmoid + clip for one pooled cell.
// ---------------------------------------------------------------------------
template <int IDX>
DEVINL void do_cell(const float (&f)[3][16], unsigned pk, int c, float* prp, float* lap) {
    unsigned px = pk >> 23;
    float vm = -FLT_MAX;
#pragma unroll
    for (int r = 0; r < 3; ++r)
#pragma unroll
        for (int dc = 0; dc < 3; ++dc)
            vm = fmaxf(vm, ((px >> (r * 3 + dc)) & 1u) ? f[r][IDX + dc] : -FLT_MAX);
    float p = __builtin_amdgcn_rcpf(1.f + __expf(-vm));
    p = fminf(fmaxf(p, 1e-6f), 1.f);
    *prp = p;
    *lap = ((pk >> c) & 1u) ? 1.f : 0.f;
}

// ---------------------------------------------------------------------------
// k_mix: CE + pool role-split blocks.
// R6 post-mortem: per-THREAD MLP (VGPR-held loads) finally worked (VGPR 80)
// and did NOT raise BW -> holding loads in VGPRs costs occupancy for nothing.
// CE role rebuilt on global_load_lds (Common-mistake #1): per-WAVE MLP at
// zero VGPR cost. 3 phases x {7 async 1KB plane loads -> LDS, vmcnt(0),
// barrier, accumulate from LDS}. ~5 blocks/CU x 4 waves x 7 KB = 140 KB
// outstanding per CU during load phases (vs ~2-10 KB before). Class order
// and se accumulation order identical to prior rounds -> bitwise-same CE.
// Pool role: R5's verified pack-based body (R6's inline bits_cell recomputed
// each cell 21x -- reverted).
// ---------------------------------------------------------------------------
__global__ __launch_bounds__(256) void k_mix(const float* __restrict__ score,
                                             const int* __restrict__ target,
                                             const unsigned* __restrict__ pack,
                                             float* __restrict__ pr,
                                             float* __restrict__ la,
                                             float* __restrict__ cov) {
    __shared__ float lds[7 * 1024];   // 28 KB: 7 planes x 1024 px (CE role)
    __shared__ float rn[4], rc[4];
    int bid = blockIdx.x;
    int t = threadIdx.x;
    int wv = t >> 6, lane = t & 63;

    if (bid < NB_CE) {
        // ---- CE role: block per 1024 consecutive pixels -------------------
        int n = bid >> 8;                       // (bid*1024) >> 18
        int bhw = (bid * 1024) & (HW_ - 1);     // pixel base within image
        const float* sp0 = score + (size_t)n * C_ * HW_ + bhw;
        int p0 = bid * 1024 + t * 4;
        int4 t4 = *(const int4*)(target + p0);

        float4 se = {0.f, 0.f, 0.f, 0.f};
        float4 stgt = {0.f, 0.f, 0.f, 0.f};
        for (int ph = 0; ph < 3; ++ph) {
#pragma unroll
            for (int u = 0; u < 7; ++u) {
                int c = ph * 7 + u;
                const float* g = sp0 + (size_t)c * HW_ + t * 4;      // per-lane
                float* l = &lds[u * 1024 + wv * 256];                // wave-uniform
                __builtin_amdgcn_global_load_lds((gas_void*)g, (las_void*)l,
                                                 16, 0, 0);
            }
            asm volatile("s_waitcnt vmcnt(0)" ::: "memory");
            __syncthreads();
#pragma unroll
            for (int u = 0; u < 7; ++u) {
                int c = ph * 7 + u;
                f4_t v = *(const f4_t*)&lds[u * 1024 + t * 4];
                se.x += __expf(v.x);
                se.y += __expf(v.y);
                se.z += __expf(v.z);
                se.w += __expf(v.w);
                if (t4.x == c) stgt.x = v.x;
                if (t4.y == c) stgt.y = v.y;
                if (t4.z == c) stgt.z = v.z;
                if (t4.w == c) stgt.w = v.w;
            }
            __syncthreads();   // WAR: next phase overwrites lds
        }

        float nll = 0.f, cnt = 0.f;
        if (t4.x != 255) { nll += __logf(se.x) - stgt.x; cnt += 1.f; }
        if (t4.y != 255) { nll += __logf(se.y) - stgt.y; cnt += 1.f; }
        if (t4.z != 255) { nll += __logf(se.z) - stgt.z; cnt += 1.f; }
        if (t4.w != 255) { nll += __logf(se.w) - stgt.w; cnt += 1.f; }

        nll = wave_sum63(nll);
        cnt = wave_sum63(cnt);
        if (lane == 63) { rn[wv] = nll; rc[wv] = cnt; }
        __syncthreads();
        if (t == 0)
            atomicAdd(&cov[NC_ * NCOV_ + 0], rn[0] + rn[1] + rn[2] + rn[3]);
        if (t == 64)
            atomicAdd(&cov[NC_ * NCOV_ + 1], rc[0] + rc[1] + rc[2] + rc[3]);
    } else {
        // ---- Pool role: thread per (n,c,i,g) (R5-verified body) -----------
        int tid = (bid - NB_CE) * 256 + t;
        if (tid >= NC_ * P_ * G_) return;
        int g = tid % G_;
        int rest = tid / G_;
        int i = rest % P_;
        int ncidx = rest / P_;
        int n = ncidx / C_;
        int c = ncidx - n * C_;

        int hl = 3 * i - 1; if (hl < 0) hl = 0;
        int b = (g == 0) ? 0 : 12 * g - 4;
        int o3 = (b + 15 < W_) ? 12 : 8;

        const float* sb = score + (size_t)ncidx * HW_ + (size_t)hl * W_ + b;
        float f[3][16];
#pragma unroll
        for (int r = 0; r < 3; ++r) {
            const float* rp = sb + r * W_;
            float4 q0 = *(const float4*)(rp);
            float4 q1 = *(const float4*)(rp + 4);
            float4 q2 = *(const float4*)(rp + 8);
            float4 q3 = *(const float4*)(rp + o3);
            f[r][0] = q0.x;  f[r][1] = q0.y;  f[r][2] = q0.z;  f[r][3] = q0.w;
            f[r][4] = q1.x;  f[r][5] = q1.y;  f[r][6] = q1.z;  f[r][7] = q1.w;
            f[r][8] = q2.x;  f[r][9] = q2.y;  f[r][10] = q2.z; f[r][11] = q2.w;
            f[r][12] = q3.x; f[r][13] = q3.y; f[r][14] = q3.z; f[r][15] = q3.w;
        }

        const unsigned* pkp = pack + n * PP_ + i * P_ + 4 * g;
        size_t ob = (size_t)ncidx * PPAD_ + (size_t)i * PROW_ + 4 * g;
        if (g == 0) {
            do_cell<0>(f, pkp[0], c, pr + ob + 0, la + ob + 0);
            do_cell<2>(f, pkp[1], c, pr + ob + 1, la + ob + 1);
            do_cell<5>(f, pkp[2], c, pr + ob + 2, la + ob + 2);
            do_cell<8>(f, pkp[3], c, pr + ob + 3, la + ob + 3);
        } else {
            do_cell<3>(f, pkp[0], c, pr + ob + 0, la + ob + 0);
            do_cell<6>(f, pkp[1], c, pr + ob + 1, la + ob + 1);
            do_cell<9>(f, pkp[2], c, pr + ob + 2, la + ob + 2);
            if (4 * g + 3 < P_)
                do_cell<12>(f, pkp[3], c, pr + ob + 3, la + ob + 3);
        }
    }
}

// ---------------------------------------------------------------------------
// k_cov v6 (unchanged from R5/R6; dropped out of top-5): global reads
// (L2-hot), grid (84, 4 chunks, 8 parts) = 2688 blocks, every part <=27
// register-resident accumulators, DPP reductions, LDS 432 B.
//   z=0: SAA d<3 (24)   z=1: SAA d>=3 (21)   z=2: SBB d<3 (24)
//   z=3: SBB d>=3 (21)  z=4..6: SAB a-row RA=z-4 (27)  z=7: s1A+s1B (18)
// ---------------------------------------------------------------------------
template <int D0, int D1>
DEVINL void cov_tri(const float* __restrict__ X, float* __restrict__ cov,
                    int nc, int r0, int rend, int s2base,
                    int tid, float (*red)[27]) {
    constexpr int NS2 = ((9 - D0) * (10 - D0) - (9 - D1) * (10 - D1)) / 2;
    constexpr int RLO = D0 / 3;
    constexpr int KOFF = tstart(D0);
    float s2[NS2];
#pragma unroll
    for (int k = 0; k < NS2; ++k) s2[k] = 0.f;

    int nitems = (rend - r0) * G_;
    for (int idx = tid; idx < nitems; idx += 256) {
        int lr = idx / G_;
        int q = idx - lr * G_;
        int x0 = q * 4;
        const float* base = X + (size_t)(r0 + lr) * PROW_ + x0;
        float v[3][8];
#pragma unroll
        for (int r = RLO; r < 3; ++r) {
            float4 u0 = *(const float4*)(base + r * PROW_);
            float4 u1 = *(const float4*)(base + r * PROW_ + 4);
            v[r][0] = u0.x; v[r][1] = u0.y; v[r][2] = u0.z; v[r][3] = u0.w;
            v[r][4] = u1.x; v[r][5] = u1.y; v[r][6] = u1.z; v[r][7] = u1.w;
        }
#pragma unroll
        for (int p = 0; p < 4; ++p) {
            if (x0 + p < Q_) {
                int k = 0;
#pragma unroll
                for (int d = D0; d < D1; ++d)
#pragma unroll
                    for (int e = d; e < 9; ++e) {
                        s2[k] += v[d / 3][p + d % 3] * v[e / 3][p + e % 3];
                        ++k;
                    }
            }
        }
    }

    int lane = tid & 63, wv = tid >> 6;
#pragma unroll
    for (int k = 0; k < NS2; ++k) {
        float v2 = wave_sum63(s2[k]);
        if (lane == 63) red[wv][k] = v2;
    }
    __syncthreads();
    if (tid < NS2) {
        float v2 = red[0][tid] + red[1][tid] + red[2][tid] + red[3][tid];
        atomicAdd(&cov[nc * NCOV_ + s2base + KOFF + tid], v2);
    }
}

template <int RA>
DEVINL void cov_ab(const float* __restrict__ A, const float* __restrict__ B,
                   float* __restrict__ cov, int nc, int r0, int rend,
                   int tid, float (*red)[27]) {
    float sab[27];
#pragma unroll
    for (int k = 0; k < 27; ++k) sab[k] = 0.f;

    int nitems = (rend - r0) * G_;
    for (int idx = tid; idx < nitems; idx += 256) {
        int lr = idx / G_;
        int q = idx - lr * G_;
        int x0 = q * 4;
        size_t off = (size_t)(r0 + lr) * PROW_ + x0;
        float a[8];
        {
            float4 u0 = *(const float4*)(A + off + RA * PROW_);
            float4 u1 = *(const float4*)(A + off + RA * PROW_ + 4);
            a[0] = u0.x; a[1] = u0.y; a[2] = u0.z; a[3] = u0.w;
            a[4] = u1.x; a[5] = u1.y; a[6] = u1.z; a[7] = u1.w;
        }
#pragma unroll
        for (int r = 0; r < 3; ++r) {
            float b[8];
            {
                float4 w0 = *(const float4*)(B + off + r * PROW_);
                float4 w1 = *(const float4*)(B + off + r * PROW_ + 4);
                b[0] = w0.x; b[1] = w0.y; b[2] = w0.z; b[3] = w0.w;
                b[4] = w1.x; b[5] = w1.y; b[6] = w1.z; b[7] = w1.w;
            }
#pragma unroll
            for (int p = 0; p < 4; ++p) {
                if (x0 + p < Q_) {
#pragma unroll
                    for (int dm = 0; dm < 3; ++dm)
#pragma unroll
                        for (int e2 = 0; e2 < 3; ++e2)
                            sab[dm * 9 + r * 3 + e2] += a[p + dm] * b[p + e2];
                }
            }
        }
    }

    int lane = tid & 63, wv = tid >> 6;
#pragma unroll
    for (int k = 0; k < 27; ++k) {
        float v2 = wave_sum63(sab[k]);
        if (lane == 63) red[wv][k] = v2;
    }
    __syncthreads();
    if (tid < 27) {
        float v2 = red[0][tid] + red[1][tid] + red[2][tid] + red[3][tid];
        atomicAdd(&cov[nc * NCOV_ + 108 + RA * 27 + tid], v2);
    }
}

DEVINL void cov_s1(const float* __restrict__ LA, const float* __restrict__ PR,
                   float* __restrict__ cov, int nc, int r0, int rend,
                   int tid, float (*red)[27]) {
    float s1a[9], s1b[9];
#pragma unroll
    for (int k = 0; k < 9; ++k) { s1a[k] = 0.f; s1b[k] = 0.f; }

    int nitems = (rend - r0) * G_;
    for (int idx = tid; idx < nitems; idx += 256) {
        int lr = idx / G_;
        int q = idx - lr * G_;
        int x0 = q * 4;
        size_t off = (size_t)(r0 + lr) * PROW_ + x0;
#pragma unroll
        for (int r = 0; r < 3; ++r) {
            float va[8], vb[8];
            {
                float4 u0 = *(const float4*)(LA + off + r * PROW_);
                float4 u1 = *(const float4*)(LA + off + r * PROW_ + 4);
                va[0] = u0.x; va[1] = u0.y; va[2] = u0.z; va[3] = u0.w;
                va[4] = u1.x; va[5] = u1.y; va[6] = u1.z; va[7] = u1.w;
                float4 w0 = *(const float4*)(PR + off + r * PROW_);
                float4 w1 = *(const float4*)(PR + off + r * PROW_ + 4);
                vb[0] = w0.x; vb[1] = w0.y; vb[2] = w0.z; vb[3] = w0.w;
                vb[4] = w1.x; vb[5] = w1.y; vb[6] = w1.z; vb[7] = w1.w;
            }
#pragma unroll
            for (int p = 0; p < 4; ++p) {
                if (x0 + p < Q_) {
#pragma unroll
                    for (int dc = 0; dc < 3; ++dc) {
                        s1a[r * 3 + dc] += va[p + dc];
                        s1b[r * 3 + dc] += vb[p + dc];
                    }
                }
            }
        }
    }

    int lane = tid & 63, wv = tid >> 6;
#pragma unroll
    for (int k = 0; k < 9; ++k) {
        float v2 = wave_sum63(s1a[k]);
        if (lane == 63) red[wv][k] = v2;
    }
#pragma unroll
    for (int k = 0; k < 9; ++k) {
        float v2 = wave_sum63(s1b[k]);
        if (lane == 63) red[wv][9 + k] = v2;
    }
    __syncthreads();
    if (tid < 18) {
        float v2 = red[0][tid] + red[1][tid] + red[2][tid] + red[3][tid];
        atomicAdd(&cov[nc * NCOV_ + tid], v2);   // 0..8 = s1A, 9..17 = s1B
    }
}

__global__ __launch_bounds__(256) void k_cov(const float* __restrict__ la,
                                             const float* __restrict__ pr,
                                             float* __restrict__ cov) {
    __shared__ float red[4][27];
    int nc = blockIdx.x;
    int chunk = blockIdx.y;
    int part = blockIdx.z;
    int r0 = chunk * RC_;
    int rend = r0 + RC_;
    if (rend > Q_) rend = Q_;
    int tid = threadIdx.x;
    const float* LA = la + (size_t)nc * PPAD_;
    const float* PR = pr + (size_t)nc * PPAD_;

    switch (part) {
        case 0: cov_tri<0, 3>(LA, cov, nc, r0, rend, 18, tid, red); break;
        case 1: cov_tri<3, 9>(LA, cov, nc, r0, rend, 18, tid, red); break;
        case 2: cov_tri<0, 3>(PR, cov, nc, r0, rend, 63, tid, red); break;
        case 3: cov_tri<3, 9>(PR, cov, nc, r0, rend, 63, tid, red); break;
        case 4: cov_ab<0>(LA, PR, cov, nc, r0, rend, tid, red); break;
        case 5: cov_ab<1>(LA, PR, cov, nc, r0, rend, tid, red); break;
        case 6: cov_ab<2>(LA, PR, cov, nc, r0, rend, tid, red); break;
        case 7: cov_s1(LA, PR, cov, nc, r0, rend, tid, red); break;
    }
}

// ---------------------------------------------------------------------------
// k_final: per-(n,c) 9x9 algebra. UNCHANGED.
// ---------------------------------------------------------------------------
__global__ __launch_bounds__(128) void k_final(const float* __restrict__ cov,
                                               float* __restrict__ out) {
    __shared__ float red[128];
    int t = threadIdx.x;
    float my = 0.f;
    if (t < NC_) {
        const float* S = cov + t * NCOV_;
        const float Lf = (float)(Q_ * Q_);  // 28561
        float sA[9], sB[9];
#pragma unroll
        for (int d = 0; d < 9; ++d) { sA[d] = S[d]; sB[d] = S[9 + d]; }
        float laC[45], M[45], Cm[81];
        {
            int k = 0;
#pragma unroll
            for (int d = 0; d < 9; ++d)
#pragma unroll
                for (int e = d; e < 9; ++e) {
                    laC[k] = S[18 + k] - sA[d] * sA[e] / Lf;
                    M[k] = S[63 + k] - sB[d] * sB[e] / Lf + (d == e ? EPS_ : 0.f);
                    ++k;
                }
#pragma unroll
            for (int d = 0; d < 9; ++d)
#pragma unroll
                for (int e = 0; e < 9; ++e)
                    Cm[d * 9 + e] = S[108 + d * 9 + e] - sA[d] * sB[e] / Lf;
        }
#pragma unroll
        for (int j = 0; j < 9; ++j) {
            float s = M[tstart(j)];
#pragma unroll
            for (int k = 0; k < j; ++k) { float l = M[tstart(k) + (j - k)]; s -= l * l; }
            float dj = sqrtf(fmaxf(s, 1e-30f));
            M[tstart(j)] = dj;
            float inv = 1.f / dj;
#pragma unroll
            for (int i = j + 1; i < 9; ++i) {
                float s2 = M[tstart(j) + (i - j)];
#pragma unroll
                for (int k = 0; k < j; ++k)
                    s2 -= M[tstart(k) + (i - k)] * M[tstart(k) + (j - k)];
                M[tstart(j) + (i - j)] = s2 * inv;
            }
        }
#pragma unroll
        for (int p = 0; p < 9; ++p) {
#pragma unroll
            for (int i = 0; i < 9; ++i) {
                float s = Cm[p * 9 + i];
#pragma unroll
                for (int k = 0; k < i; ++k)
                    s -= M[tstart(k) + (i - k)] * Cm[p * 9 + k];
                Cm[p * 9 + i] = s / M[tstart(i)];
            }
        }
#pragma unroll
        for (int d = 0; d < 9; ++d)
#pragma unroll
            for (int e = d; e < 9; ++e) {
                float s = 0.f;
#pragma unroll
                for (int i = 0; i < 9; ++i) s += Cm[d * 9 + i] * Cm[e * 9 + i];
                laC[tstart(d) + (e - d)] -= s;
                if (d == e) laC[tstart(d)] += EPS_;
            }
        float rmi = 0.f;
#pragma unroll
        for (int j = 0; j < 9; ++j) {
            float s = laC[tstart(j)];
#pragma unroll
            for (int k = 0; k < j; ++k) { float l = laC[tstart(k) + (j - k)]; s -= l * l; }
            float dj = sqrtf(fmaxf(s, 0.f));
            laC[tstart(j)] = dj;
            float inv = 1.f / fmaxf(dj, 1e-30f);
#pragma unroll
            for (int i = j + 1; i < 9; ++i) {
                float s2 = laC[tstart(j) + (i - j)];
#pragma unroll
                for (int k = 0; k < j; ++k)
                    s2 -= laC[tstart(k) + (i - k)] * laC[tstart(k) + (j - k)];
                laC[tstart(j) + (i - j)] = s2 * inv;
            }
            rmi += __logf(dj + 1e-8f);
        }
        my = rmi;
    }
    red[t] = my;
    __syncthreads();
#pragma unroll
    for (int o = 64; o > 0; o >>= 1) {
        if (t < o) red[t] += red[t + o];
        __syncthreads();
    }
    if (t == 0) {
        float rmi_total = red[0] / 36.f;  // / (N * HALF_D)
        float ce = cov[NC_ * NCOV_ + 0] / cov[NC_ * NCOV_ + 1];
        out[0] = 0.5f * ce + 0.5f * rmi_total;
    }
}

extern "C" void kernel_launch(void* const* d_in, const int* in_sizes, int n_in,
                              void* d_out, int out_size, void* d_ws, size_t ws_size,
                              hipStream_t stream) {
    const float* score = (const float*)d_in[0];
    const int* target = (const int*)d_in[1];
    float* pr = (float*)d_ws;
    float* la = pr + (size_t)NC_ * PPAD_;
    float* cov = la + (size_t)NC_ * PPAD_;              // NC_*NCOV_ + 2 floats
    unsigned* pack = (unsigned*)(cov + NC_ * NCOV_ + 2);

    k_bits<<<dim3((N_ * PP_ + 255) / 256), dim3(256), 0, stream>>>(target, pack, cov);
    k_mix<<<dim3(NB_CE + NB_PL), dim3(256), 0, stream>>>(score, target, pack, pr, la, cov);
    k_cov<<<dim3(NC_, 4, 8), dim3(256), 0, stream>>>(la, pr, cov);
    k_final<<<dim3(1), dim3(128), 0, stream>>>(cov, (float*)d_out);
}